// Round 13
// baseline (287.675 us; speedup 1.0000x reference)
//
#include <hip/hip_runtime.h>
#include <cstdint>
#include <cstddef>

// Problem constants (match reference setup_inputs)
#define B_TOK   16384
#define IN_DIM  2048
#define D_DIM   1024
#define NEXP    3
#define TOPK    2
#define H1_DIM  1024
#define H2_DIM  512

typedef __bf16 bf16x8 __attribute__((ext_vector_type(8)));
typedef float  f32x16 __attribute__((ext_vector_type(16)));
typedef unsigned short ushort8_t __attribute__((ext_vector_type(8)));

__device__ __forceinline__ unsigned short f2bf(float f) {
    unsigned int u = __builtin_bit_cast(unsigned int, f);
    return (unsigned short)((u + 0x7fffu + ((u >> 16) & 1u)) >> 16);
}
__device__ __forceinline__ float bf2f(unsigned short v) {
    return __builtin_bit_cast(float, (unsigned int)v << 16);
}

// async global->LDS, 16B per lane. LDS dest is wave-uniform base + lane*16;
// global source address IS per-lane (enables gather + inverse-swizzle).
__device__ __forceinline__ void glds16(const void* gsrc, void* ldst) {
    __builtin_amdgcn_global_load_lds(
        (__attribute__((address_space(1))) void*)(gsrc),
        (__attribute__((address_space(3))) void*)(ldst),
        16, 0, 0);
}

// shared 64x64 transpose-tile body (256 threads), tile scratch provided
__device__ __forceinline__ void transpose_tile_256(
    const float* __restrict__ Wp, unsigned short* __restrict__ Wtp,
    int K, int N, int n0, int k0, int t, unsigned short (*tile)[68])
{
    int nn = (t & 15) * 4;
    int kk = t >> 4;
    #pragma unroll
    for (int rr = 0; rr < 4; ++rr) {
        int k = kk + rr * 16;
        float4 v = *(const float4*)(Wp + (size_t)(k0 + k) * N + (n0 + nn));
        tile[k][nn + 0] = f2bf(v.x);
        tile[k][nn + 1] = f2bf(v.y);
        tile[k][nn + 2] = f2bf(v.z);
        tile[k][nn + 3] = f2bf(v.w);
    }
    __syncthreads();
    int n  = t >> 2;
    int kb = (t & 3) * 16;
    ushort8_t o0, o1;
    #pragma unroll
    for (int i = 0; i < 8; ++i) o0[i] = tile[kb + i][n];
    #pragma unroll
    for (int i = 0; i < 8; ++i) o1[i] = tile[kb + 8 + i][n];
    unsigned short* dst = Wtp + (size_t)(n0 + n) * K + (k0 + kb);
    *(ushort8_t*)dst = o0;
    *(ushort8_t*)(dst + 8) = o1;
}

// ---------------- fused prepass ----------------
// blocks [0,2048)      : x f32 -> bf16 (grid-stride)
// blocks [2048,3584)   : W1 [E][K][N] f32 -> [E][N][K] bf16 transpose
// blocks [3584,3648)   : token routing (cnt/list/inv); list pre-zeroed by
//                        host-side memset, so pad slots already hold token 0.
// W2/W3 transposes ride inside the L1 GEMM launch (idle-CU capacity).
__global__ __launch_bounds__(256) void prepass(
    const float* __restrict__ x, unsigned short* __restrict__ xb,
    const float* __restrict__ W1s, unsigned short* __restrict__ W1d,
    const int* __restrict__ tidx,
    int* __restrict__ cnt, int* __restrict__ list, int* __restrict__ inv)
{
    const int bid = blockIdx.x;
    const int t = threadIdx.x;

    if (bid < 2048) {
        // ---- convert x ----
        const size_t n = (size_t)B_TOK * IN_DIM;
        const size_t stride = (size_t)2048 * 256 * 8;
        size_t i = ((size_t)bid * 256 + t) * 8;
        for (; i < n; i += stride) {
            float4 a = *(const float4*)(x + i);
            float4 b = *(const float4*)(x + i + 4);
            ushort8_t o;
            o[0] = f2bf(a.x); o[1] = f2bf(a.y); o[2] = f2bf(a.z); o[3] = f2bf(a.w);
            o[4] = f2bf(b.x); o[5] = f2bf(b.y); o[6] = f2bf(b.z); o[7] = f2bf(b.w);
            *(ushort8_t*)(xb + i) = o;
        }
    } else if (bid < 3584) {
        // ---- transpose W1 (512 tiles/expert) ----
        __shared__ unsigned short tile[64][68];
        int g = bid - 2048;
        int e = g / 512;
        int r = g % 512;
        const int ntx = H1_DIM >> 6;   // 16
        int n0 = (r % ntx) * 64, k0 = (r / ntx) * 64;
        transpose_tile_256(W1s + (size_t)e * IN_DIM * H1_DIM,
                           W1d + (size_t)e * H1_DIM * IN_DIM,
                           IN_DIM, H1_DIM, n0, k0, t, tile);
    } else {
        // ---- route tokens ----
        __shared__ int lcnt[NEXP];
        __shared__ int lbase[NEXP];
        __shared__ int ltok[NEXP][256];
        int b = (bid - 3584) * 256 + t;
        if (t < NEXP) lcnt[t] = 0;
        __syncthreads();
        int i0 = tidx[b * TOPK + 0], i1 = tidx[b * TOPK + 1];
        #pragma unroll
        for (int e = 0; e < NEXP; ++e) {
            if (i0 == e || i1 == e) {
                int s = atomicAdd(&lcnt[e], 1);
                ltok[e][s] = b;
            }
        }
        __syncthreads();
        if (t < NEXP) lbase[t] = atomicAdd(&cnt[t], lcnt[t]);
        __syncthreads();
        #pragma unroll
        for (int e = 0; e < NEXP; ++e) {
            int n = lcnt[e], base = lbase[e];
            for (int s = t; s < n; s += 256) {
                int tk = ltok[e][s];
                list[e * B_TOK + base + s] = tk;
                inv[e * B_TOK + tk] = base + s;
            }
        }
    }
}

// combine: out[tok] = p0 * y[i0][inv[i0][tok]] + p1 * y[i1][inv[i1][tok]]
// y planes are bf16. Handles i0==i1 naturally. Writes EVERY output element.
__global__ __launch_bounds__(256) void combine_out(
    const float* __restrict__ probs, const int* __restrict__ tidx,
    const int* __restrict__ inv, const unsigned short* __restrict__ y, size_t ypl,
    float* __restrict__ out)
{
    int gid = blockIdx.x * 256 + threadIdx.x;
    int tok = gid >> 7;              // 128 threads per token
    int dc  = (gid & 127) << 3;      // 8 cols per thread
    float p0 = probs[tok * TOPK + 0], p1 = probs[tok * TOPK + 1];
    int   i0 = tidx [tok * TOPK + 0], i1 = tidx [tok * TOPK + 1];
    size_t r0 = (size_t)i0 * ypl + (size_t)inv[(size_t)i0 * B_TOK + tok] * D_DIM + dc;
    size_t r1 = (size_t)i1 * ypl + (size_t)inv[(size_t)i1 * B_TOK + tok] * D_DIM + dc;
    ushort8_t a = *(const ushort8_t*)(y + r0);
    ushort8_t b = *(const ushort8_t*)(y + r1);
    float4 o0, o1;
    o0.x = p0 * bf2f(a[0]) + p1 * bf2f(b[0]);
    o0.y = p0 * bf2f(a[1]) + p1 * bf2f(b[1]);
    o0.z = p0 * bf2f(a[2]) + p1 * bf2f(b[2]);
    o0.w = p0 * bf2f(a[3]) + p1 * bf2f(b[3]);
    o1.x = p0 * bf2f(a[4]) + p1 * bf2f(b[4]);
    o1.y = p0 * bf2f(a[5]) + p1 * bf2f(b[5]);
    o1.z = p0 * bf2f(a[6]) + p1 * bf2f(b[6]);
    o1.w = p0 * bf2f(a[7]) + p1 * bf2f(b[7]);
    float* op = out + (size_t)tok * D_DIM + dc;
    *(float4*)op = o0;
    *(float4*)(op + 4) = o1;
}

// ------------- 8-window 256x256 GEMM, 32x32x16 MFMA variant ----------------
// C = act(A[slots,K] @ Bt[N,K]^T + bias) -> bf16 planes.
// Same frozen window/stage/vmcnt LEDGER as rounds 8-12 (byte-identical LDS
// movement); only the register-level fragment mapping changed:
// mfma_f32_32x32x16_bf16 (m119: +17% FLOP/cyc vs 16x16x32). Per window the
// wave computes its 32x64 quadrant-slab as 2 col-tiles of 32x32 over 4 K-steps
// of 16 (8 MFMA vs 16). A-frag: lane row=l&31, 16B unit=2ks+(l>>5); B-frag
// mirrors with col=l&31. XOR-swizzle operand (row&7=l&7) unchanged -> same
// conflict-free profile. C/D (m74/m101-verified): col=l&31,
// row=(r&3)+8*(r>>2)+4*(l>>5). acc 8x f32x16 = 128 regs, operands 48 regs --
// identical register budget.
// XTRA=1 (L1 launch only): trailing blocks transpose W2/W3 on idle CUs.
template<int ACT, int GATHER, int XTRA>
__global__ __launch_bounds__(512, 2) void gemm8(
    const unsigned short* __restrict__ Ab, size_t Aplane,  // bf16 [slots][K] (per-expert plane if !GATHER)
    const unsigned short* __restrict__ Bb,                 // bf16 [E][N][K]
    const float* __restrict__ biasb,                       // [E][N]
    unsigned short* __restrict__ Hb,                       // bf16 planes out
    size_t plane,                                          // elements per plane
    const int* __restrict__ listb,                         // [E][B_TOK]
    const int* __restrict__ cntb,                          // [E] actual count
    int N, int K, int NT, int e0, int NTOT,
    const float* __restrict__ W2s, const float* __restrict__ W3s,
    unsigned short* __restrict__ W2d, unsigned short* __restrict__ W3d)
{
    __shared__ char smem[131072];   // GEMM: A [0,64K) B [64K,128K); XTRA: tiles

    const int bid  = blockIdx.x;
    const int tid  = threadIdx.x;

    if constexpr (XTRA) {
        if (bid >= NTOT) {
            // two 64x64 transpose tiles per block (threads 0-255 / 256-511)
            int half = tid >> 8;
            int t    = tid & 255;
            int g = (bid - NTOT) * 2 + half;   // [0,768): 384 W2 then 384 W3
            const float* W; unsigned short* Wt; int K2, N2, e, r;
            if (g < 384) { e = g / 128; r = g % 128; W = W2s; Wt = W2d; K2 = H1_DIM; N2 = H2_DIM; }
            else { g -= 384; e = g / 128; r = g % 128; W = W3s; Wt = W3d; K2 = H2_DIM; N2 = D_DIM; }
            const int ntx = N2 >> 6;
            int n0 = (r % ntx) * 64, k0 = (r / ntx) * 64;
            unsigned short (*tile)[68] = (unsigned short(*)[68])(smem + half * 8704);
            transpose_tile_256(W + (size_t)e * K2 * N2, Wt + (size_t)e * N2 * K2,
                               K2, N2, n0, k0, t, tile);
            return;
        }
    }

    // bijective tile->XCD mapping: xcd=bid&7; XCD x walks A-tiles {x,x+8,...}
    // with the NT N-blocks of each A-tile consecutive (L2 A-reuse); live
    // tiles (early-exit) spread evenly across XCDs.
    const int xcd  = bid & 7;
    const int slot = bid >> 3;
    const int q    = slot / NT;
    const int nt   = slot % NT;
    const int ti   = q * 8 + xcd;
    const int e    = e0 + (ti >> 6);
    const int mt   = ti & 63;
    const int bm   = mt << 8;
    const int cp   = (cntb[e] + 255) & ~255;   // padded count, inline
    if (bm >= cp) return;
    const int bn   = nt << 8;

    const int lane = tid & 63;
    const int w    = tid >> 6;      // wave 0..7
    const int wl3  = w & 3;         // A 32-row band within half
    const int wn1  = w >> 2;        // B 64-col band within half
    const int l31  = lane & 31;
    const int lhi  = lane >> 5;     // 0/1: K-half within a 16-K step
    const int ug8  = (((tid & 7) ^ ((tid >> 3) & 7)) << 3);          // src swz (shorts)
    // fragment read swizzle per K-step ks: unit = 2*ks + lhi, XOR row&7 (=lane&7)
    const int sk0  = (((0 + lhi) ^ (lane & 7)) << 4);
    const int sk1  = (((2 + lhi) ^ (lane & 7)) << 4);
    const int sk2  = (((4 + lhi) ^ (lane & 7)) << 4);
    const int sk3  = (((6 + lhi) ^ (lane & 7)) << 4);

    const int* listp = listb + (size_t)e * B_TOK;
    const unsigned short* Ae = Ab + (size_t)e * Aplane;
    const unsigned short* Be = Bb + (size_t)e * ((size_t)N * K);
    const float* biasp = biasb + (size_t)e * N;

    // per-thread stage source pointers: half h, load j covers tile row
    // h*128 + j*64 + (tid>>3); 16B unit = (tid&7) ^ ((tid>>3)&7)  (inverse swz)
    const unsigned short* sA[2][2];
    const unsigned short* sB[2][2];
    #pragma unroll
    for (int h = 0; h < 2; ++h)
        #pragma unroll
        for (int j = 0; j < 2; ++j) {
            int lrow = h * 128 + j * 64 + (tid >> 3);
            int arow;
            if constexpr (GATHER) arow = listp[bm + lrow];
            else                  arow = bm + lrow;
            sA[h][j] = Ae + (size_t)arow * K + ug8;
            sB[h][j] = Be + (size_t)(bn + lrow) * K + ug8;
        }

    char* const stA = smem + (w << 10);            // + db*32768 + h*16384 (+8192 for j=1)
    char* const stB = smem + 65536 + (w << 10);
    // read bases: A row = wl3*32 + l31 (+Qm*128); B col-row = wn1*64 + tn*32 + l31 (+Qn*128)
    const char* const rA = smem + (wl3 * 32 + l31) * 128;
    const char* const rB = smem + 65536 + (wn1 * 64 + l31) * 128;

    f32x16 acc[2][2][2] = {};   // [Qm][Qn][tn]
    bf16x8 av[4];               // A frags per K-step ks=0..3
    bf16x8 bv[2][4];            // B frags [tn][ks]

#define STA(db, h, kt) do {                                                     \
    glds16(sA[h][0] + (size_t)(kt) * 64, stA + (db) * 32768 + (h) * 16384);     \
    glds16(sA[h][1] + (size_t)(kt) * 64, stA + (db) * 32768 + (h) * 16384 + 8192); } while (0)
#define STB(db, h, kt) do {                                                     \
    glds16(sB[h][0] + (size_t)(kt) * 64, stB + (db) * 32768 + (h) * 16384);     \
    glds16(sB[h][1] + (size_t)(kt) * 64, stB + (db) * 32768 + (h) * 16384 + 8192); } while (0)

// k-half operand loads: kk=0 -> ks{0,1}, kk=1 -> ks{2,3} (2 A + 4 B reads)
#define LAk(db, Qm, kk) do {                                                    \
    av[2*(kk)+0] = *(const bf16x8*)(rA + (db)*32768 + (Qm)*16384 + ((kk) ? sk2 : sk0)); \
    av[2*(kk)+1] = *(const bf16x8*)(rA + (db)*32768 + (Qm)*16384 + ((kk) ? sk3 : sk1)); \
    } while (0)
#define LBk(db, Qn, kk) do {                                                    \
    _Pragma("unroll")                                                           \
    for (int tn = 0; tn < 2; ++tn) {                                            \
        bv[tn][2*(kk)+0] = *(const bf16x8*)(rB + (db)*32768 + (Qn)*16384 + tn*4096 + ((kk) ? sk2 : sk0)); \
        bv[tn][2*(kk)+1] = *(const bf16x8*)(rB + (db)*32768 + (Qn)*16384 + tn*4096 + ((kk) ? sk3 : sk1)); \
    } } while (0)

// 4-MFMA group (32x32x16) for one k-half of quadrant (Qm,Qn)
#define GK(Qm, Qn, kk) do {                                                     \
    _Pragma("unroll")                                                           \
    for (int tn = 0; tn < 2; ++tn)                                              \
        _Pragma("unroll")                                                       \
        for (int i = 0; i < 2; ++i)                                             \
            acc[Qm][Qn][tn] = __builtin_amdgcn_mfma_f32_32x32x16_bf16(          \
                av[2*(kk)+i], bv[tn][2*(kk)+i], acc[Qm][Qn][tn], 0, 0, 0);      \
    } while (0)

// window: stage; [counted vmcnt]; then k-split MFMA with next-window loads
// pinned mid-cluster via sched_barrier(0); single barrier at end.
#define WINDOW(Qm, Qn, STAGE_STMT, VM_STMT, LK0, LK1) do {                      \
    STAGE_STMT;                                                                 \
    VM_STMT;                                                                    \
    __builtin_amdgcn_s_setprio(1);                                              \
    GK(Qm, Qn, 0);                                                              \
    __builtin_amdgcn_sched_barrier(0);                                          \
    LK0;                                                                        \
    __builtin_amdgcn_sched_barrier(0);                                          \
    GK(Qm, Qn, 1);                                                              \
    __builtin_amdgcn_sched_barrier(0);                                          \
    LK1;                                                                        \
    __builtin_amdgcn_s_setprio(0);                                              \
    __builtin_amdgcn_sched_barrier(0);                                          \
    __builtin_amdgcn_s_barrier();                                               \
} while (0)

    const int nkt = K >> 6;           // 64-wide K-tiles (even for all layers)
    // prologue: buf0 = tile0 full; buf1 h0 = tile1 {A,B}; then first reads
    STA(0, 0, 0); STA(0, 1, 0); STB(0, 0, 0); STB(0, 1, 0);
    STA(1, 0, 1); STB(1, 0, 1);
    asm volatile("s_waitcnt vmcnt(4)" ::: "memory");   // buf0's 8 loads landed
    __builtin_amdgcn_s_barrier();
    LAk(0, 1, 0); LAk(0, 1, 1); LBk(0, 0, 0); LBk(0, 0, 1);  // regs for window 1

    const int niter = nkt >> 1;
    for (int it = 0; it < niter; ++it) {
        const int t1 = 2 * it + 1;
        const int t2 = (2 * it + 2 < nkt) ? 2 * it + 2 : nkt - 1;  // clamped: dead stages
        const int t3 = (2 * it + 3 < nkt) ? 2 * it + 3 : nkt - 1;
        WINDOW(1, 0, STA(1, 1, t1), ((void)0), LAk(0, 0, 0), LAk(0, 0, 1));
        WINDOW(0, 0, STB(1, 1, t1), ((void)0), LBk(0, 1, 0), LBk(0, 1, 1));
        WINDOW(0, 1, STA(0, 0, t2), ((void)0), LAk(0, 1, 0), LAk(0, 1, 1));
        WINDOW(1, 1, STB(0, 0, t2),
               asm volatile("s_waitcnt vmcnt(4)" ::: "memory"),
               LAk(1, 1, 0); LBk(1, 0, 0), LAk(1, 1, 1); LBk(1, 0, 1));
        WINDOW(1, 0, STA(0, 1, t2), ((void)0), LAk(1, 0, 0), LAk(1, 0, 1));
        WINDOW(0, 0, STB(0, 1, t2), ((void)0), LBk(1, 1, 0), LBk(1, 1, 1));
        WINDOW(0, 1, STA(1, 0, t3), ((void)0), LAk(1, 1, 0), LAk(1, 1, 1));
        WINDOW(1, 1, STB(1, 0, t3),
               asm volatile("s_waitcnt vmcnt(4)" ::: "memory"),
               LAk(0, 1, 0); LBk(0, 0, 0), LAk(0, 1, 1); LBk(0, 0, 1));
    }
    asm volatile("s_waitcnt vmcnt(0)" ::: "memory");   // drain tail stages

    // epilogue. C/D (m74/m101-verified): col = lane&31,
    // row = (r&3) + 8*(r>>2) + 4*(lane>>5), r in [0,16).
    float bsv[2][2];
    #pragma unroll
    for (int Qn = 0; Qn < 2; ++Qn)
        #pragma unroll
        for (int tn = 0; tn < 2; ++tn)
            bsv[Qn][tn] = biasp[bn + Qn * 128 + wn1 * 64 + tn * 32 + l31];

    unsigned short* Hp = Hb + (size_t)e * plane;
    #pragma unroll
    for (int Qm = 0; Qm < 2; ++Qm)
    #pragma unroll
    for (int Qn = 0; Qn < 2; ++Qn)
    #pragma unroll
    for (int tn = 0; tn < 2; ++tn) {
        int col = bn + Qn * 128 + wn1 * 64 + tn * 32 + l31;
        #pragma unroll
        for (int r = 0; r < 16; ++r) {
            int row = bm + Qm * 128 + wl3 * 32 + (r & 3) + 8 * (r >> 2) + 4 * lhi;
            float v = acc[Qm][Qn][tn][r] + bsv[Qn][tn];
            if (ACT) v = v > 0.f ? v : 0.2f * v;
            Hp[(size_t)row * N + col] = f2bf(v);
        }
    }
#undef WINDOW
#undef GK
#undef LAk
#undef LBk
#undef STA
#undef STB
}

// ---------------- host launch ----------------

extern "C" void kernel_launch(void* const* d_in, const int* in_sizes, int n_in,
                              void* d_out, int out_size, void* d_ws, size_t ws_size,
                              hipStream_t stream)
{
    const float* x     = (const float*)d_in[0];
    // d_in[1] = gate (unused by reference forward)
    const float* probs = (const float*)d_in[2];
    const int*   tidx  = (const int*)d_in[3];
    const float* W1    = (const float*)d_in[4];
    const float* b1    = (const float*)d_in[5];
    const float* W2    = (const float*)d_in[6];
    const float* b2    = (const float*)d_in[7];
    const float* W3    = (const float*)d_in[8];
    const float* b3    = (const float*)d_in[9];
    float* out = (float*)d_out;

    // workspace layout (bytes); total ~340 MB of the 512 MiB d_ws.
    // lst and cnt are ADJACENT so one memset zeroes both (list pad slots
    // must be token 0; cnt must start at 0).
    char* ws = (char*)d_ws;
    const size_t xb_off  = 0;
    const size_t w1t_off = xb_off  + (size_t)B_TOK * IN_DIM * 2;
    const size_t w2t_off = w1t_off + (size_t)NEXP * IN_DIM * H1_DIM * 2;
    const size_t w3t_off = w2t_off + (size_t)NEXP * H1_DIM * H2_DIM * 2;
    const size_t h1_off  = w3t_off + (size_t)NEXP * H2_DIM * D_DIM * 2;
    const size_t h2_off  = h1_off  + (size_t)NEXP * B_TOK * H1_DIM * 2;
    const size_t y_off   = h2_off  + (size_t)NEXP * B_TOK * H2_DIM * 2;
    const size_t li_off  = y_off   + (size_t)NEXP * B_TOK * D_DIM * 2;   // y bf16
    const size_t cn_off  = li_off  + (size_t)NEXP * B_TOK * 4;
    const size_t iv_off  = cn_off  + 256;

    unsigned short* xb  = (unsigned short*)(ws + xb_off);
    unsigned short* W1t = (unsigned short*)(ws + w1t_off);
    unsigned short* W2t = (unsigned short*)(ws + w2t_off);
    unsigned short* W3t = (unsigned short*)(ws + w3t_off);
    unsigned short* h1  = (unsigned short*)(ws + h1_off);
    unsigned short* h2  = (unsigned short*)(ws + h2_off);
    unsigned short* y   = (unsigned short*)(ws + y_off);
    int*            lst = (int*)(ws + li_off);
    int*            cnt = (int*)(ws + cn_off);
    int*            inv = (int*)(ws + iv_off);

    // zero list + cnt in one shot (192 KB + 256 B)
    hipMemsetAsync(lst, 0, (size_t)NEXP * B_TOK * 4 + 256, stream);

    // fused prepass: convert x || transpose W1 || route tokens
    prepass<<<3648, 256, 0, stream>>>(x, xb, W1, W1t, tidx, cnt, lst, inv);

    const size_t h1pl = (size_t)B_TOK * H1_DIM;
    const size_t h2pl = (size_t)B_TOK * H2_DIM;
    const size_t ypl  = (size_t)B_TOK * D_DIM;

    // L1 grouped across experts: gathered x rows -> h1 planes (bf16).
    // +384 trailing blocks transpose W2/W3 on idle CUs during the GEMM.
    gemm8<1, 1, 1><<<dim3(NEXP * 64 * 4 + 384), 512, 0, stream>>>(
        xb, 0, W1t, b1, h1, h1pl,
        lst, cnt, H1_DIM, IN_DIM, 4, 0, NEXP * 64 * 4,
        W2, W3, W2t, W3t);
    // L2 grouped: h1 planes -> h2 planes (bf16)
    gemm8<1, 0, 0><<<dim3(NEXP * 64 * 2), 512, 0, stream>>>(
        h1, h1pl, W2t, b2, h2, h2pl,
        lst, cnt, H2_DIM, H1_DIM, 2, 0, NEXP * 64 * 2,
        nullptr, nullptr, nullptr, nullptr);
    // L3 grouped: h2 planes -> compact y planes (bf16, bias applied, no weight)
    gemm8<0, 0, 0><<<dim3(NEXP * 64 * 4), 512, 0, stream>>>(
        h2, h2pl, W3t, b3, y, ypl,
        lst, cnt, D_DIM, H2_DIM, 4, 0, NEXP * 64 * 4,
        nullptr, nullptr, nullptr, nullptr);
    // combine: out[tok] = p0*y[i0][slot0] + p1*y[i1][slot1]
    combine_out<<<dim3(B_TOK * 128 / 256), 256, 0, stream>>>(
        probs, tidx, inv, y, ypl, out);
}

// Round 14
// 272.740 us; speedup vs baseline: 1.0548x; 1.0548x over previous
//
#include <hip/hip_runtime.h>
#include <cstdint>
#include <cstddef>

// Problem constants (match reference setup_inputs)
#define B_TOK   16384
#define IN_DIM  2048
#define D_DIM   1024
#define NEXP    3
#define TOPK    2
#define H1_DIM  1024
#define H2_DIM  512

typedef __bf16 bf16x8 __attribute__((ext_vector_type(8)));
typedef float  f32x4  __attribute__((ext_vector_type(4)));
typedef unsigned short ushort8_t __attribute__((ext_vector_type(8)));

__device__ __forceinline__ unsigned short f2bf(float f) {
    unsigned int u = __builtin_bit_cast(unsigned int, f);
    return (unsigned short)((u + 0x7fffu + ((u >> 16) & 1u)) >> 16);
}
__device__ __forceinline__ float bf2f(unsigned short v) {
    return __builtin_bit_cast(float, (unsigned int)v << 16);
}

// async global->LDS, 16B per lane. LDS dest is wave-uniform base + lane*16;
// global source address IS per-lane (enables gather + inverse-swizzle).
__device__ __forceinline__ void glds16(const void* gsrc, void* ldst) {
    __builtin_amdgcn_global_load_lds(
        (__attribute__((address_space(1))) void*)(gsrc),
        (__attribute__((address_space(3))) void*)(ldst),
        16, 0, 0);
}

// shared 64x64 transpose-tile body (256 threads), tile scratch provided
__device__ __forceinline__ void transpose_tile_256(
    const float* __restrict__ Wp, unsigned short* __restrict__ Wtp,
    int K, int N, int n0, int k0, int t, unsigned short (*tile)[68])
{
    int nn = (t & 15) * 4;
    int kk = t >> 4;
    #pragma unroll
    for (int rr = 0; rr < 4; ++rr) {
        int k = kk + rr * 16;
        float4 v = *(const float4*)(Wp + (size_t)(k0 + k) * N + (n0 + nn));
        tile[k][nn + 0] = f2bf(v.x);
        tile[k][nn + 1] = f2bf(v.y);
        tile[k][nn + 2] = f2bf(v.z);
        tile[k][nn + 3] = f2bf(v.w);
    }
    __syncthreads();
    int n  = t >> 2;
    int kb = (t & 3) * 16;
    ushort8_t o0, o1;
    #pragma unroll
    for (int i = 0; i < 8; ++i) o0[i] = tile[kb + i][n];
    #pragma unroll
    for (int i = 0; i < 8; ++i) o1[i] = tile[kb + 8 + i][n];
    unsigned short* dst = Wtp + (size_t)(n0 + n) * K + (k0 + kb);
    *(ushort8_t*)dst = o0;
    *(ushort8_t*)(dst + 8) = o1;
}

// ---------------- fused prepass ----------------
// blocks [0,2048)      : x f32 -> bf16 (grid-stride)
// blocks [2048,3584)   : W1 [E][K][N] f32 -> [E][N][K] bf16 transpose
// blocks [3584,3648)   : token routing (cnt/list/inv)
// W2/W3 transposes ride inside the L1 GEMM launch (idle-CU capacity).
__global__ __launch_bounds__(256) void prepass(
    const float* __restrict__ x, unsigned short* __restrict__ xb,
    const float* __restrict__ W1s, unsigned short* __restrict__ W1d,
    const int* __restrict__ tidx,
    int* __restrict__ cnt, int* __restrict__ list, int* __restrict__ inv)
{
    const int bid = blockIdx.x;
    const int t = threadIdx.x;

    if (bid < 2048) {
        // ---- convert x ----
        const size_t n = (size_t)B_TOK * IN_DIM;
        const size_t stride = (size_t)2048 * 256 * 8;
        size_t i = ((size_t)bid * 256 + t) * 8;
        for (; i < n; i += stride) {
            float4 a = *(const float4*)(x + i);
            float4 b = *(const float4*)(x + i + 4);
            ushort8_t o;
            o[0] = f2bf(a.x); o[1] = f2bf(a.y); o[2] = f2bf(a.z); o[3] = f2bf(a.w);
            o[4] = f2bf(b.x); o[5] = f2bf(b.y); o[6] = f2bf(b.z); o[7] = f2bf(b.w);
            *(ushort8_t*)(xb + i) = o;
        }
    } else if (bid < 3584) {
        // ---- transpose W1 (512 tiles/expert) ----
        __shared__ unsigned short tile[64][68];
        int g = bid - 2048;
        int e = g / 512;
        int r = g % 512;
        const int ntx = H1_DIM >> 6;   // 16
        int n0 = (r % ntx) * 64, k0 = (r / ntx) * 64;
        transpose_tile_256(W1s + (size_t)e * IN_DIM * H1_DIM,
                           W1d + (size_t)e * H1_DIM * IN_DIM,
                           IN_DIM, H1_DIM, n0, k0, t, tile);
    } else {
        // ---- route tokens ----
        __shared__ int lcnt[NEXP];
        __shared__ int lbase[NEXP];
        __shared__ int ltok[NEXP][256];
        int b = (bid - 3584) * 256 + t;
        if (t < NEXP) lcnt[t] = 0;
        __syncthreads();
        int i0 = tidx[b * TOPK + 0], i1 = tidx[b * TOPK + 1];
        #pragma unroll
        for (int e = 0; e < NEXP; ++e) {
            if (i0 == e || i1 == e) {
                int s = atomicAdd(&lcnt[e], 1);
                ltok[e][s] = b;
            }
        }
        __syncthreads();
        if (t < NEXP) lbase[t] = atomicAdd(&cnt[t], lcnt[t]);
        __syncthreads();
        #pragma unroll
        for (int e = 0; e < NEXP; ++e) {
            int n = lcnt[e], base = lbase[e];
            for (int s = t; s < n; s += 256) {
                int tk = ltok[e][s];
                list[e * B_TOK + base + s] = tk;
                inv[e * B_TOK + tk] = base + s;
            }
        }
    }
}

// combine: out[tok] = p0 * y[i0][inv[i0][tok]] + p1 * y[i1][inv[i1][tok]]
// y planes are bf16. Handles i0==i1 naturally. Writes EVERY output element.
__global__ __launch_bounds__(256) void combine_out(
    const float* __restrict__ probs, const int* __restrict__ tidx,
    const int* __restrict__ inv, const unsigned short* __restrict__ y, size_t ypl,
    float* __restrict__ out)
{
    int gid = blockIdx.x * 256 + threadIdx.x;
    int tok = gid >> 7;              // 128 threads per token
    int dc  = (gid & 127) << 3;      // 8 cols per thread
    float p0 = probs[tok * TOPK + 0], p1 = probs[tok * TOPK + 1];
    int   i0 = tidx [tok * TOPK + 0], i1 = tidx [tok * TOPK + 1];
    size_t r0 = (size_t)i0 * ypl + (size_t)inv[(size_t)i0 * B_TOK + tok] * D_DIM + dc;
    size_t r1 = (size_t)i1 * ypl + (size_t)inv[(size_t)i1 * B_TOK + tok] * D_DIM + dc;
    ushort8_t a = *(const ushort8_t*)(y + r0);
    ushort8_t b = *(const ushort8_t*)(y + r1);
    float4 o0, o1;
    o0.x = p0 * bf2f(a[0]) + p1 * bf2f(b[0]);
    o0.y = p0 * bf2f(a[1]) + p1 * bf2f(b[1]);
    o0.z = p0 * bf2f(a[2]) + p1 * bf2f(b[2]);
    o0.w = p0 * bf2f(a[3]) + p1 * bf2f(b[3]);
    o1.x = p0 * bf2f(a[4]) + p1 * bf2f(b[4]);
    o1.y = p0 * bf2f(a[5]) + p1 * bf2f(b[5]);
    o1.z = p0 * bf2f(a[6]) + p1 * bf2f(b[6]);
    o1.w = p0 * bf2f(a[7]) + p1 * bf2f(b[7]);
    float* op = out + (size_t)tok * D_DIM + dc;
    *(float4*)op = o0;
    *(float4*)(op + 4) = o1;
}

// ---------------- 8-window 256x256 GEMM, k-split interleaved ----------------
// C = act(A[slots,K] @ Bt[N,K]^T + bias) -> bf16 planes.
// EXACT round-8/10/11/12 passing GEMM (frozen; 8 consistent measurements at
// 42-43% MfmaUtil = structural ceiling under the 256-reg/2-wave cap).
// Round-13 ERRATA: the 32x32x16 variant's fragment reads were 4-way
// bank-conflicted (12.85M/dispatch, -9%) -- 16x16x32's lane>>4-dependent
// swizzle unit is the conflict-free pattern. Reverted.
// GATHER pad rows clamp to token 0 in-kernel (list pad-zeroing not needed).
// XTRA=1 (L1 launch only): trailing blocks transpose W2/W3 on idle CUs.
template<int ACT, int GATHER, int XTRA>
__global__ __launch_bounds__(512, 2) void gemm8(
    const unsigned short* __restrict__ Ab, size_t Aplane,  // bf16 [slots][K] (per-expert plane if !GATHER)
    const unsigned short* __restrict__ Bb,                 // bf16 [E][N][K]
    const float* __restrict__ biasb,                       // [E][N]
    unsigned short* __restrict__ Hb,                       // bf16 planes out
    size_t plane,                                          // elements per plane
    const int* __restrict__ listb,                         // [E][B_TOK]
    const int* __restrict__ cntb,                          // [E] actual count
    int N, int K, int NT, int e0, int NTOT,
    const float* __restrict__ W2s, const float* __restrict__ W3s,
    unsigned short* __restrict__ W2d, unsigned short* __restrict__ W3d)
{
    __shared__ char smem[131072];   // GEMM: A [0,64K) B [64K,128K); XTRA: tiles

    const int bid  = blockIdx.x;
    const int tid  = threadIdx.x;

    if constexpr (XTRA) {
        if (bid >= NTOT) {
            // two 64x64 transpose tiles per block (threads 0-255 / 256-511)
            int half = tid >> 8;
            int t    = tid & 255;
            int g = (bid - NTOT) * 2 + half;   // [0,768): 384 W2 then 384 W3
            const float* W; unsigned short* Wt; int K2, N2, e, r;
            if (g < 384) { e = g / 128; r = g % 128; W = W2s; Wt = W2d; K2 = H1_DIM; N2 = H2_DIM; }
            else { g -= 384; e = g / 128; r = g % 128; W = W3s; Wt = W3d; K2 = H2_DIM; N2 = D_DIM; }
            const int ntx = N2 >> 6;
            int n0 = (r % ntx) * 64, k0 = (r / ntx) * 64;
            unsigned short (*tile)[68] = (unsigned short(*)[68])(smem + half * 8704);
            transpose_tile_256(W + (size_t)e * K2 * N2, Wt + (size_t)e * N2 * K2,
                               K2, N2, n0, k0, t, tile);
            return;
        }
    }

    // bijective tile->XCD mapping: xcd=bid&7; XCD x walks A-tiles {x,x+8,...}
    // with the NT N-blocks of each A-tile consecutive (L2 A-reuse); live
    // tiles (early-exit) spread evenly across XCDs.
    const int xcd  = bid & 7;
    const int slot = bid >> 3;
    const int q    = slot / NT;
    const int nt   = slot % NT;
    const int ti   = q * 8 + xcd;
    const int e    = e0 + (ti >> 6);
    const int mt   = ti & 63;
    const int bm   = mt << 8;
    const int C    = cntb[e];
    const int cp   = (C + 255) & ~255;   // padded count, inline
    if (bm >= cp) return;
    const int bn   = nt << 8;

    const int lane = tid & 63;
    const int w    = tid >> 6;      // wave 0..7
    const int wl3  = w & 3;         // A 32-row band within half
    const int wn1  = w >> 2;        // B 64-col band within half
    const int l15  = lane & 15;
    const int ug8  = (((tid & 7) ^ ((tid >> 3) & 7)) << 3);          // src swz (shorts)
    const int sw0  = ((((lane >> 4) + 0) ^ (lane & 7)) << 4);        // read swz k0 (bytes)
    const int sw1  = ((((lane >> 4) + 4) ^ (lane & 7)) << 4);        // read swz k1 (bytes)

    const int* listp = listb + (size_t)e * B_TOK;
    const unsigned short* Ae = Ab + (size_t)e * Aplane;
    const unsigned short* Be = Bb + (size_t)e * ((size_t)N * K);
    const float* biasp = biasb + (size_t)e * N;

    // per-thread stage source pointers: half h, load j covers tile row
    // h*128 + j*64 + (tid>>3); 16B unit = (tid&7) ^ ((tid>>3)&7)  (inverse swz)
    const unsigned short* sA[2][2];
    const unsigned short* sB[2][2];
    #pragma unroll
    for (int h = 0; h < 2; ++h)
        #pragma unroll
        for (int j = 0; j < 2; ++j) {
            int lrow = h * 128 + j * 64 + (tid >> 3);
            int arow;
            if constexpr (GATHER) arow = (bm + lrow < C) ? listp[bm + lrow] : 0;
            else                  arow = bm + lrow;
            sA[h][j] = Ae + (size_t)arow * K + ug8;
            sB[h][j] = Be + (size_t)(bn + lrow) * K + ug8;
        }

    char* const stA = smem + (w << 10);            // + db*32768 + h*16384 (+8192 for j=1)
    char* const stB = smem + 65536 + (w << 10);
    const char* const rA = smem + (wl3 * 32 + l15) * 128;           // + db*32768 + Qm*16384 + ml*2048 + sw
    const char* const rB = smem + 65536 + (wn1 * 64 + l15) * 128;   // + db*32768 + Qn*16384 + nl*2048 + sw

    f32x4 acc[2][2][2][4] = {};   // [Qm][ml][Qn][nl]
    bf16x8 av[2][2];              // A operand regs [ml][k]
    bf16x8 bv[4][2];              // B operand regs [nl][k]

#define STA(db, h, kt) do {                                                     \
    glds16(sA[h][0] + (size_t)(kt) * 64, stA + (db) * 32768 + (h) * 16384);     \
    glds16(sA[h][1] + (size_t)(kt) * 64, stA + (db) * 32768 + (h) * 16384 + 8192); } while (0)
#define STB(db, h, kt) do {                                                     \
    glds16(sB[h][0] + (size_t)(kt) * 64, stB + (db) * 32768 + (h) * 16384);     \
    glds16(sB[h][1] + (size_t)(kt) * 64, stB + (db) * 32768 + (h) * 16384 + 8192); } while (0)

// k-sliced operand loads (2 reads for A-slice, 4 for B-slice)
#define LAk(db, Qm, kk) do {                                                    \
    _Pragma("unroll")                                                           \
    for (int ml = 0; ml < 2; ++ml)                                              \
        av[ml][kk] = *(const bf16x8*)(rA + (db)*32768 + (Qm)*16384 + ml*2048    \
                                      + ((kk) ? sw1 : sw0));                    \
    } while (0)
#define LBk(db, Qn, kk) do {                                                    \
    _Pragma("unroll")                                                           \
    for (int nl = 0; nl < 4; ++nl)                                              \
        bv[nl][kk] = *(const bf16x8*)(rB + (db)*32768 + (Qn)*16384 + nl*2048    \
                                      + ((kk) ? sw1 : sw0));                    \
    } while (0)

// 8-MFMA group for one k-slice of quadrant (Qm,Qn)
#define GK(Qm, Qn, kk) do {                                                     \
    _Pragma("unroll")                                                           \
    for (int ml = 0; ml < 2; ++ml)                                              \
        _Pragma("unroll")                                                       \
        for (int nl = 0; nl < 4; ++nl)                                          \
            acc[Qm][ml][Qn][nl] = __builtin_amdgcn_mfma_f32_16x16x32_bf16(      \
                av[ml][kk], bv[nl][kk], acc[Qm][ml][Qn][nl], 0, 0, 0);          \
    } while (0)

// window: stage; [counted vmcnt]; then k-split MFMA with next-window loads
// pinned mid-cluster via sched_barrier(0); single barrier at end.
#define WINDOW(Qm, Qn, STAGE_STMT, VM_STMT, LK0, LK1) do {                      \
    STAGE_STMT;                                                                 \
    VM_STMT;                                                                    \
    __builtin_amdgcn_s_setprio(1);                                              \
    GK(Qm, Qn, 0);                                                              \
    __builtin_amdgcn_sched_barrier(0);                                          \
    LK0;                                                                        \
    __builtin_amdgcn_sched_barrier(0);                                          \
    GK(Qm, Qn, 1);                                                              \
    __builtin_amdgcn_sched_barrier(0);                                          \
    LK1;                                                                        \
    __builtin_amdgcn_s_setprio(0);                                              \
    __builtin_amdgcn_sched_barrier(0);                                          \
    __builtin_amdgcn_s_barrier();                                               \
} while (0)

    const int nkt = K >> 6;           // 64-wide K-tiles (even for all layers)
    // prologue: buf0 = tile0 full; buf1 h0 = tile1 {A,B}; then first reads
    STA(0, 0, 0); STA(0, 1, 0); STB(0, 0, 0); STB(0, 1, 0);
    STA(1, 0, 1); STB(1, 0, 1);
    asm volatile("s_waitcnt vmcnt(4)" ::: "memory");   // buf0's 8 loads landed
    __builtin_amdgcn_s_barrier();
    LAk(0, 1, 0); LAk(0, 1, 1); LBk(0, 0, 0); LBk(0, 0, 1);  // regs for window 1

    const int niter = nkt >> 1;
    for (int it = 0; it < niter; ++it) {
        const int t1 = 2 * it + 1;
        const int t2 = (2 * it + 2 < nkt) ? 2 * it + 2 : nkt - 1;  // clamped: dead stages
        const int t3 = (2 * it + 3 < nkt) ? 2 * it + 3 : nkt - 1;
        WINDOW(1, 0, STA(1, 1, t1), ((void)0), LAk(0, 0, 0), LAk(0, 0, 1));
        WINDOW(0, 0, STB(1, 1, t1), ((void)0), LBk(0, 1, 0), LBk(0, 1, 1));
        WINDOW(0, 1, STA(0, 0, t2), ((void)0), LAk(0, 1, 0), LAk(0, 1, 1));
        WINDOW(1, 1, STB(0, 0, t2),
               asm volatile("s_waitcnt vmcnt(4)" ::: "memory"),
               LAk(1, 1, 0); LBk(1, 0, 0), LAk(1, 1, 1); LBk(1, 0, 1));
        WINDOW(1, 0, STA(0, 1, t2), ((void)0), LAk(1, 0, 0), LAk(1, 0, 1));
        WINDOW(0, 0, STB(0, 1, t2), ((void)0), LBk(1, 1, 0), LBk(1, 1, 1));
        WINDOW(0, 1, STA(1, 0, t3), ((void)0), LAk(1, 1, 0), LAk(1, 1, 1));
        WINDOW(1, 1, STB(1, 0, t3),
               asm volatile("s_waitcnt vmcnt(4)" ::: "memory"),
               LAk(0, 1, 0); LBk(0, 0, 0), LAk(0, 1, 1); LBk(0, 0, 1));
    }
    asm volatile("s_waitcnt vmcnt(0)" ::: "memory");   // drain tail stages

    // epilogue. C/D (m89-verified): col = lane&15 (B side), row = (lane>>4)*4+jj
    const int rl = (lane >> 4) << 2;
    float bsv[2][4];
    #pragma unroll
    for (int Qn = 0; Qn < 2; ++Qn)
        #pragma unroll
        for (int nl = 0; nl < 4; ++nl)
            bsv[Qn][nl] = biasp[bn + Qn * 128 + wn1 * 64 + nl * 16 + l15];

    unsigned short* Hp = Hb + (size_t)e * plane;
    #pragma unroll
    for (int Qm = 0; Qm < 2; ++Qm)
    #pragma unroll
    for (int ml = 0; ml < 2; ++ml)
    #pragma unroll
    for (int jj = 0; jj < 4; ++jj) {
        int srow = bm + Qm * 128 + wl3 * 32 + ml * 16 + rl + jj;
        size_t ro = (size_t)srow * N;
        #pragma unroll
        for (int Qn = 0; Qn < 2; ++Qn)
        #pragma unroll
        for (int nl = 0; nl < 4; ++nl) {
            int col = bn + Qn * 128 + wn1 * 64 + nl * 16 + l15;
            float v = acc[Qm][ml][Qn][nl][jj] + bsv[Qn][nl];
            if (ACT) v = v > 0.f ? v : 0.2f * v;
            Hp[ro + col] = f2bf(v);
        }
    }
#undef WINDOW
#undef GK
#undef LAk
#undef LBk
#undef STA
#undef STB
}

// ---------------- host launch ----------------

extern "C" void kernel_launch(void* const* d_in, const int* in_sizes, int n_in,
                              void* d_out, int out_size, void* d_ws, size_t ws_size,
                              hipStream_t stream)
{
    const float* x     = (const float*)d_in[0];
    // d_in[1] = gate (unused by reference forward)
    const float* probs = (const float*)d_in[2];
    const int*   tidx  = (const int*)d_in[3];
    const float* W1    = (const float*)d_in[4];
    const float* b1    = (const float*)d_in[5];
    const float* W2    = (const float*)d_in[6];
    const float* b2    = (const float*)d_in[7];
    const float* W3    = (const float*)d_in[8];
    const float* b3    = (const float*)d_in[9];
    float* out = (float*)d_out;

    // workspace layout (bytes); total ~340 MB of the 512 MiB d_ws.
    char* ws = (char*)d_ws;
    const size_t xb_off  = 0;
    const size_t w1t_off = xb_off  + (size_t)B_TOK * IN_DIM * 2;
    const size_t w2t_off = w1t_off + (size_t)NEXP * IN_DIM * H1_DIM * 2;
    const size_t w3t_off = w2t_off + (size_t)NEXP * H1_DIM * H2_DIM * 2;
    const size_t h1_off  = w3t_off + (size_t)NEXP * H2_DIM * D_DIM * 2;
    const size_t h2_off  = h1_off  + (size_t)NEXP * B_TOK * H1_DIM * 2;
    const size_t y_off   = h2_off  + (size_t)NEXP * B_TOK * H2_DIM * 2;
    const size_t li_off  = y_off   + (size_t)NEXP * B_TOK * D_DIM * 2;   // y bf16
    const size_t cn_off  = li_off  + (size_t)NEXP * B_TOK * 4;
    const size_t iv_off  = cn_off  + 256;

    unsigned short* xb  = (unsigned short*)(ws + xb_off);
    unsigned short* W1t = (unsigned short*)(ws + w1t_off);
    unsigned short* W2t = (unsigned short*)(ws + w2t_off);
    unsigned short* W3t = (unsigned short*)(ws + w3t_off);
    unsigned short* h1  = (unsigned short*)(ws + h1_off);
    unsigned short* h2  = (unsigned short*)(ws + h2_off);
    unsigned short* y   = (unsigned short*)(ws + y_off);
    int*            lst = (int*)(ws + li_off);
    int*            cnt = (int*)(ws + cn_off);
    int*            inv = (int*)(ws + iv_off);

    // zero cnt only (pad rows clamp to token 0 in-kernel)
    hipMemsetAsync(cnt, 0, 256, stream);

    // fused prepass: convert x || transpose W1 || route tokens
    prepass<<<3648, 256, 0, stream>>>(x, xb, W1, W1t, tidx, cnt, lst, inv);

    const size_t h1pl = (size_t)B_TOK * H1_DIM;
    const size_t h2pl = (size_t)B_TOK * H2_DIM;
    const size_t ypl  = (size_t)B_TOK * D_DIM;

    // L1 grouped across experts: gathered x rows -> h1 planes (bf16).
    // +384 trailing blocks transpose W2/W3 on idle CUs during the GEMM.
    gemm8<1, 1, 1><<<dim3(NEXP * 64 * 4 + 384), 512, 0, stream>>>(
        xb, 0, W1t, b1, h1, h1pl,
        lst, cnt, H1_DIM, IN_DIM, 4, 0, NEXP * 64 * 4,
        W2, W3, W2t, W3t);
    // L2 grouped: h1 planes -> h2 planes (bf16)
    gemm8<1, 0, 0><<<dim3(NEXP * 64 * 2), 512, 0, stream>>>(
        h1, h1pl, W2t, b2, h2, h2pl,
        lst, cnt, H2_DIM, H1_DIM, 2, 0, NEXP * 64 * 2,
        nullptr, nullptr, nullptr, nullptr);
    // L3 grouped: h2 planes -> compact y planes (bf16, bias applied, no weight)
    gemm8<0, 0, 0><<<dim3(NEXP * 64 * 4), 512, 0, stream>>>(
        h2, h2pl, W3t, b3, y, ypl,
        lst, cnt, D_DIM, H2_DIM, 4, 0, NEXP * 64 * 4,
        nullptr, nullptr, nullptr, nullptr);
    // combine: out[tok] = p0*y[i0][slot0] + p1*y[i1][slot1]
    combine_out<<<dim3(B_TOK * 128 / 256), 256, 0, stream>>>(
        probs, tidx, inv, y, ypl, out);
}